// Round 6
// baseline (231.551 us; speedup 1.0000x reference)
//
#include <hip/hip_runtime.h>
#include <hip/hip_fp16.h>
#include <math.h>
#include <float.h>

#define M_G 100000
#define M_PAD 100096         // 782 * 128
#define N_Q 2048
#define DIM 256
#define NMT 782              // 128-row gallery tiles
#define NQT 8                // 256-col query tiles
#define NG2 1564             // 64-row groups = NMT*2
#define GSTRIDE 1568         // padded group stride for bmaxT rows
#define MARGIN 0.008f        // > 2*(2^-11 RN + FTZ 6e-5*sum|q| + accum) fp16 bound

typedef _Float16 f16x8 __attribute__((ext_vector_type(8)));
typedef float f32x4 __attribute__((ext_vector_type(4)));

// ws layout (bytes)
#define WS_GP    0                   // 782 tiles * 64KB = 51,249,152
#define WS_QP    51249152            // 8 tiles * 128KB  =  1,048,576
#define WS_BMAX  52297728            // 2048*1568*4      = 12,845,056

__device__ inline unsigned pack_h2(float a, float b) {
    __half ha = __float2half(a), hb = __float2half(b);   // RN
    return (unsigned)*(unsigned short*)&ha | ((unsigned)*(unsigned short*)&hb << 16);
}
__device__ inline void gload_lds16(const void* gsrc, void* ldst) {
    __builtin_amdgcn_global_load_lds(
        (const __attribute__((address_space(1))) unsigned int*)gsrc,
        (__attribute__((address_space(3))) unsigned int*)ldst, 16, 0, 0);
}

#define BAR __builtin_amdgcn_s_barrier()
#define VMCNT0 { asm volatile("s_waitcnt vmcnt(0)" ::: "memory"); \
                 __builtin_amdgcn_sched_barrier(0); }

// Normalize rows, fp32->fp16 (RN), store in per-K-step swizzled LDS image
// layout. Gallery tile = 128 rows: chunk (mt*4+kt) of 1024 uint4, granule
// (rl, gg) at rl*8 + (gg ^ (rl&7)). Query tile = 256 rows: chunk (qt*4+kt)
// of 2048 uint4, same granule rule. Gallery pad rows (>=M_G) zeroed.
__global__ __launch_bounds__(256) void pack_kernel(
    const float* __restrict__ g, const float* __restrict__ q,
    uint4* __restrict__ gp, uint4* __restrict__ qp)
{
    const int b = blockIdx.x;
    const int w4 = threadIdx.x >> 6, lane = threadIdx.x & 63;
    const bool isg = b < (M_PAD / 4);
    const int row = (isg ? b : b - M_PAD / 4) * 4 + w4;
    const bool real = !isg || row < M_G;
    const float* src = isg ? g + (size_t)row * DIM : q + (size_t)row * DIM;

    float inv = 0.0f;
    if (real) {
        float4 v = ((const float4*)src)[lane];
        float ss = v.x * v.x + v.y * v.y + v.z * v.z + v.w * v.w;
        #pragma unroll
        for (int o = 32; o; o >>= 1) ss += __shfl_xor(ss, o);
        inv = 1.0f / fmaxf(sqrtf(ss), 1e-12f);
    }
    if (lane < 32) {
        uint4 w = make_uint4(0u, 0u, 0u, 0u);
        if (real) {
            float4 a = ((const float4*)src)[lane * 2];
            float4 c = ((const float4*)src)[lane * 2 + 1];
            w.x = pack_h2(a.x * inv, a.y * inv);
            w.y = pack_h2(a.z * inv, a.w * inv);
            w.z = pack_h2(c.x * inv, c.y * inv);
            w.w = pack_h2(c.z * inv, c.w * inv);
        }
        const int kt = lane >> 3, gg = lane & 7;
        if (isg) {
            int mt = row >> 7, rl = row & 127;
            gp[(size_t)(mt * 4 + kt) * 1024 + rl * 8 + (gg ^ (rl & 7))] = w;
        } else {
            int qt = row >> 8, rl = row & 255;
            qp[(size_t)(qt * 4 + kt) * 2048 + rl * 8 + (gg ^ (rl & 7))] = w;
        }
    }
}

// Phase A: fp16 MFMA GEMM. Block = 128 gallery rows x 256 queries, 4 waves
// (each 128 x 64), BK=64, single-buffered 48KB LDS.
// launch_bounds(256,3): 3 blocks/CU (144KB LDS, 12 waves/CU) so the per-block
// {stage drain -> LDS-read burst -> MFMA burst} serial phases interleave
// across blocks; per-CU demand then binds on the MFMA pipe, not the drain.
__global__ __launch_bounds__(256, 3) void scoreA_kernel(
    const uint4* __restrict__ gp, const uint4* __restrict__ qp,
    float* __restrict__ bmaxT)
{
    __shared__ __align__(16) char lds[49152];   // As 16KB | Bs 32KB

    const int bid = blockIdx.x;
    const int xcd = bid & 7, j = bid >> 3;
    const int csz = (xcd < 6) ? 98 : 97;
    if (j >= csz * NQT) return;
    const int cbase = (xcd < 6) ? xcd * 98 : 588 + (xcd - 6) * 97;
    const int qt = j & 7;
    const int mt = cbase + (j >> 3);

    const int tid = threadIdx.x;
    const int w = tid >> 6, lane = tid & 63;
    const int r16 = lane & 15, rhi = lane >> 4;

    const uint4* ga = gp + (size_t)mt * 4096;
    const uint4* qb = qp + (size_t)qt * 8192;

    f32x4 acc[8][4];
    #pragma unroll
    for (int f = 0; f < 8; ++f)
        #pragma unroll
        for (int n = 0; n < 4; ++n) acc[f][n] = (f32x4){0.f, 0.f, 0.f, 0.f};
    f16x8 aR[8], bR[4];

    for (int kt = 0; kt < 4; ++kt) {
        // stage A (1024 uint4) + B (2048 uint4), linear
        #pragma unroll
        for (int p = 0; p < 4; ++p)
            gload_lds16(ga + (size_t)kt * 1024 + p * 256 + tid,
                        lds + (p * 256 + tid) * 16);
        #pragma unroll
        for (int p = 0; p < 8; ++p)
            gload_lds16(qb + (size_t)kt * 2048 + p * 256 + tid,
                        lds + 16384 + (p * 256 + tid) * 16);
        VMCNT0;
        BAR;
        #pragma unroll
        for (int kk = 0; kk < 2; ++kk) {
            #pragma unroll
            for (int f = 0; f < 8; ++f) {
                int row = f * 16 + r16;
                aR[f] = *(const f16x8*)(lds + row * 128 +
                                        (((kk * 4 + rhi) ^ (row & 7)) << 4));
            }
            #pragma unroll
            for (int f = 0; f < 4; ++f) {
                int row = w * 64 + f * 16 + r16;
                bR[f] = *(const f16x8*)(lds + 16384 + row * 128 +
                                        (((kk * 4 + rhi) ^ (row & 7)) << 4));
            }
            #pragma unroll
            for (int f = 0; f < 8; ++f)
                #pragma unroll
                for (int fj = 0; fj < 4; ++fj)
                    acc[f][fj] = __builtin_amdgcn_mfma_f32_16x16x32_f16(
                        aR[f], bR[fj], acc[f][fj], 0, 0, 0);
        }
        BAR;
    }

    // epilogue: per-query max over each 64-row group (frags 0-3, 4-7)
    #pragma unroll
    for (int g2 = 0; g2 < 2; ++g2) {
        float cm[4] = {-FLT_MAX, -FLT_MAX, -FLT_MAX, -FLT_MAX};
        #pragma unroll
        for (int f = 0; f < 4; ++f) {
            int fr = g2 * 4 + f;
            #pragma unroll
            for (int jj = 0; jj < 4; ++jj) {
                int row = mt * 128 + fr * 16 + rhi * 4 + jj;
                bool valid = row < M_G;
                #pragma unroll
                for (int fj = 0; fj < 4; ++fj)
                    cm[fj] = fmaxf(cm[fj], valid ? acc[fr][fj][jj] : -FLT_MAX);
            }
        }
        #pragma unroll
        for (int fj = 0; fj < 4; ++fj) {
            float v = cm[fj];
            v = fmaxf(v, __shfl_xor(v, 16));
            v = fmaxf(v, __shfl_xor(v, 32));
            if (lane < 16) {
                int qn = qt * 256 + w * 64 + fj * 16 + lane;
                bmaxT[(size_t)qn * GSTRIDE + mt * 2 + g2] = v;
            }
        }
    }
}

// Phase B: s1 scan + candidate collection + exact fp32 rescore.
__global__ __launch_bounds__(256) void phaseB_kernel(
    const float* __restrict__ q, const float* __restrict__ g,
    const float* __restrict__ bmaxT,
    const int* __restrict__ cat, const int* __restrict__ shp,
    int* __restrict__ out)
{
    __shared__ __align__(16) float qrow[DIM];
    __shared__ int glist[NG2];
    __shared__ int ng;
    __shared__ float smax[4];
    __shared__ float rbs[4];
    __shared__ int rbi[4];

    const int qi = blockIdx.x;
    const int tid = threadIdx.x;
    const int lane = tid & 63, wid = tid >> 6;
    if (tid < 64)
        *(float4*)&qrow[tid * 4] = *(const float4*)(q + (size_t)qi * DIM + tid * 4);
    if (tid == 0) ng = 0;

    float m = -FLT_MAX;
    for (int gr = tid; gr < NG2; gr += 256)
        m = fmaxf(m, bmaxT[(size_t)qi * GSTRIDE + gr]);
    #pragma unroll
    for (int o = 32; o; o >>= 1) m = fmaxf(m, __shfl_xor(m, o));
    if (lane == 0) smax[wid] = m;
    __syncthreads();
    const float thr = fmaxf(fmaxf(smax[0], smax[1]), fmaxf(smax[2], smax[3])) - MARGIN;

    for (int gr = tid; gr < NG2; gr += 256)
        if (bmaxT[(size_t)qi * GSTRIDE + gr] >= thr)
            glist[atomicAdd(&ng, 1)] = gr;
    __syncthreads();

    float bs = -FLT_MAX;
    int bi = 0x7fffffff;
    const int r = tid >> 2, p = tid & 3;
    const int n = ng;
    for (int i = 0; i < n; ++i) {
        int mm = glist[i] * 64 + r;
        if (mm < M_G) {
            const float* grow = g + (size_t)mm * DIM + p * 64;
            const float* qr = qrow + p * 64;
            float s = 0.f, ssq = 0.f;
            #pragma unroll
            for (int jj = 0; jj < 16; ++jj) {
                float4 gv = *(const float4*)(grow + jj * 4);
                float4 qv = *(const float4*)(qr + jj * 4);
                s += gv.x * qv.x + gv.y * qv.y + gv.z * qv.z + gv.w * qv.w;
                ssq += gv.x * gv.x + gv.y * gv.y + gv.z * gv.z + gv.w * gv.w;
            }
            s += __shfl_xor(s, 1);  s += __shfl_xor(s, 2);
            ssq += __shfl_xor(ssq, 1);  ssq += __shfl_xor(ssq, 2);
            s *= 1.0f / fmaxf(sqrtf(ssq), 1e-12f);
            if (p == 0 && (s > bs || (s == bs && mm < bi))) { bs = s; bi = mm; }
        }
    }
    #pragma unroll
    for (int o = 1; o < 64; o <<= 1) {
        float os = __shfl_xor(bs, o);
        int oi = __shfl_xor(bi, o);
        if (os > bs || (os == bs && oi < bi)) { bs = os; bi = oi; }
    }
    if (lane == 0) { rbs[wid] = bs; rbi[wid] = bi; }
    __syncthreads();
    if (tid == 0) {
        #pragma unroll
        for (int ww = 1; ww < 4; ++ww)
            if (rbs[ww] > bs || (rbs[ww] == bs && rbi[ww] < bi)) { bs = rbs[ww]; bi = rbi[ww]; }
        out[qi] = cat[bi];
        out[N_Q + qi] = shp[bi];
    }
}

extern "C" void kernel_launch(void* const* d_in, const int* in_sizes, int n_in,
                              void* d_out, int out_size, void* d_ws, size_t ws_size,
                              hipStream_t stream) {
    const float* q = (const float*)d_in[0];    // [2048,256] fp32
    const float* g = (const float*)d_in[1];    // [100000,256] fp32
    const int* cat = (const int*)d_in[2];      // [100000] int32
    const int* shp = (const int*)d_in[3];      // [100000] int32
    int* out = (int*)d_out;                    // [2048 cat | 2048 shape] int32

    char* ws = (char*)d_ws;
    uint4* gp    = (uint4*)(ws + WS_GP);
    uint4* qp    = (uint4*)(ws + WS_QP);
    float* bmaxT = (float*)(ws + WS_BMAX);

    pack_kernel<<<M_PAD / 4 + N_Q / 4, 256, 0, stream>>>(g, q, gp, qp);
    scoreA_kernel<<<8 * 98 * NQT, 256, 0, stream>>>(gp, qp, bmaxT);
    phaseB_kernel<<<N_Q, 256, 0, stream>>>(q, g, bmaxT, cat, shp, out);
}

// Round 7
// 161.082 us; speedup vs baseline: 1.4375x; 1.4375x over previous
//
#include <hip/hip_runtime.h>
#include <hip/hip_fp16.h>
#include <math.h>
#include <float.h>

#define M_G 100000
#define M_PAD 100032         // 1563 * 64
#define NT64 1563            // 64-row gallery tiles
#define N_Q 2048
#define DIM 256
#define NG 3126              // 32-row groups = NT64*2
#define GSTR 3136            // padded group stride (halves) per query row
#define MARGIN 0.009f        // 2*(2^-11 RN) fp16 dot bound + fp16-bmax quant + slack

typedef _Float16 f16x8 __attribute__((ext_vector_type(8)));
typedef float f32x4 __attribute__((ext_vector_type(4)));

// ws layout (bytes)
#define WS_GP 0                        // 1563 * 32768 = 51,216,384
#define WS_QP 51216384                 // 8 * 131072   =  1,048,576
#define WS_BM 52264960                 // 2048*3136*2  = 12,845,056
// total ~65.1 MB

__device__ inline unsigned pack_h2(float a, float b) {
    __half ha = __float2half(a), hb = __float2half(b);   // RN
    return (unsigned)*(unsigned short*)&ha | ((unsigned)*(unsigned short*)&hb << 16);
}
__device__ inline void gload_lds16(const void* gsrc, void* ldst) {
    __builtin_amdgcn_global_load_lds(
        (const __attribute__((address_space(1))) unsigned int*)gsrc,
        (__attribute__((address_space(3))) unsigned int*)ldst, 16, 0, 0);
}

#define BAR __builtin_amdgcn_s_barrier()
#define VMCNT(n) { asm volatile("s_waitcnt vmcnt(" #n ")" ::: "memory"); \
                   __builtin_amdgcn_sched_barrier(0); }

// Normalize rows, fp32->fp16 (RN), store swizzled LDS-image layout.
// Gallery: 64-row tiles; chunk (mt64*4+kt) of 512 uint4; granule (rl∈[0,64),gg)
// at rl*8 + (gg ^ (rl&7)). Queries: 256-row tiles; chunk (qt*4+kt) of 2048
// uint4, rl∈[0,256). Gallery pad rows (>=M_G) zeroed.
__global__ __launch_bounds__(256) void pack_kernel(
    const float* __restrict__ g, const float* __restrict__ q,
    uint4* __restrict__ gp, uint4* __restrict__ qp)
{
    const int b = blockIdx.x;
    const int w4 = threadIdx.x >> 6, lane = threadIdx.x & 63;
    const bool isg = b < (M_PAD / 4);
    const int row = (isg ? b : b - M_PAD / 4) * 4 + w4;
    const bool real = !isg || row < M_G;
    const float* src = isg ? g + (size_t)row * DIM : q + (size_t)row * DIM;

    float inv = 0.0f;
    if (real) {
        float4 v = ((const float4*)src)[lane];
        float ss = v.x * v.x + v.y * v.y + v.z * v.z + v.w * v.w;
        #pragma unroll
        for (int o = 32; o; o >>= 1) ss += __shfl_xor(ss, o);
        inv = 1.0f / fmaxf(sqrtf(ss), 1e-12f);
    }
    if (lane < 32) {
        uint4 w = make_uint4(0u, 0u, 0u, 0u);
        if (real) {
            float4 a = ((const float4*)src)[lane * 2];
            float4 c = ((const float4*)src)[lane * 2 + 1];
            w.x = pack_h2(a.x * inv, a.y * inv);
            w.y = pack_h2(a.z * inv, a.w * inv);
            w.z = pack_h2(c.x * inv, c.y * inv);
            w.w = pack_h2(c.z * inv, c.w * inv);
        }
        const int kt = lane >> 3, gg = lane & 7;
        if (isg) {
            int mt = row >> 6, rl = row & 63;
            gp[((size_t)mt * 4 + kt) * 512 + rl * 8 + (gg ^ (rl & 7))] = w;
        } else {
            int qt = row >> 8, rl = row & 255;
            qp[((size_t)qt * 4 + kt) * 2048 + rl * 8 + (gg ^ (rl & 7))] = w;
        }
    }
}

#define STAGE32(dstbase, src) { const uint4* s_ = (src); _Pragma("unroll") \
  for (int p_ = 0; p_ < 4; ++p_) \
    gload_lds16(s_ + p_ * 512 + tid, lds + (dstbase) + (p_ * 512 + tid) * 16); }

#define READ_BP(KT, bufbase) { _Pragma("unroll") \
  for (int nj = 0; nj < 4; ++nj) { \
    const char* p_ = lds + (bufbase) + (wc * 64 + nj * 16 + r16) * 128; \
    bR[KT][0][nj] = *(const f16x8*)(p_ + sw0); \
    bR[KT][1][nj] = *(const f16x8*)(p_ + sw1); } }

// Phase A: Q-stationary M-streaming fp16 MFMA. 256 blocks (8 qt x 32 mchunks),
// 512 thr = 8 waves (2m x 4n). Query frags (256 q x 256 k per block; 64 q per
// wave) live in 128 VGPRs, fully unrolled static indices. Gallery streams as
// 64-row tiles through 2x32KB double-buffered LDS; stage(t+1) issued one full
// iteration before its counted vmcnt(4) wait -> near-zero drain stall.
// bid%8 = mchunk%8: the 8 qt-blocks of a chunk share one XCD's L2.
__global__ __launch_bounds__(512, 2) void scoreA_kernel(
    const uint4* __restrict__ gp, const uint4* __restrict__ qp,
    unsigned short* __restrict__ bmaxH)
{
    extern __shared__ char lds[];   // 65536: buf0 [0,32K) | buf1 [32K,64K)

    const int bid = blockIdx.x;
    const int qt = bid >> 5, mc = bid & 31;
    const int nt = (mc < 27) ? 49 : 48;
    const int t0 = (mc < 27) ? mc * 49 : 1323 + (mc - 27) * 48;

    const int tid = threadIdx.x;
    const int wid = tid >> 6, lane = tid & 63;
    const int wr = wid >> 2, wc = wid & 3;          // 2m x 4n wave grid
    const int r16 = lane & 15, rhi = lane >> 4;
    const int sw0 = ((rhi ^ (r16 & 7)) << 4);       // k-granule swizzle, kk=0
    const int sw1 = (((4 + rhi) ^ (r16 & 7)) << 4); // kk=1

    const uint4* qsrc = qp + (size_t)qt * 8192;

    // ---- prologue: load all B (query) fragments into registers ----
    f16x8 bR[4][2][4];
    STAGE32(0,     qsrc + 0 * 2048);
    STAGE32(32768, qsrc + 1 * 2048);
    VMCNT(4); BAR;                   // qp0 ready
    READ_BP(0, 0); BAR;
    STAGE32(0, qsrc + 2 * 2048);
    VMCNT(4); BAR;                   // qp1 ready
    READ_BP(1, 32768); BAR;
    STAGE32(32768, qsrc + 3 * 2048);
    VMCNT(4); BAR;                   // qp2 ready
    READ_BP(2, 0); BAR;
    STAGE32(0, gp + (size_t)t0 * 2048);
    VMCNT(4); BAR;                   // qp3 ready
    READ_BP(3, 32768); BAR;
    VMCNT(0); BAR;                   // A(t0) ready in buf0

    // ---- main loop: stream gallery tiles ----
    for (int t = 0; t < nt; ++t) {
        const int mtile = t0 + t;
        const int cur = (t & 1) << 15;
        const int nxt = cur ^ 32768;
        if (t + 1 < nt) STAGE32(nxt, gp + (size_t)(mtile + 1) * 2048);

        f32x4 acc[2][4];
        #pragma unroll
        for (int mi = 0; mi < 2; ++mi)
            #pragma unroll
            for (int nj = 0; nj < 4; ++nj) acc[mi][nj] = (f32x4){0.f, 0.f, 0.f, 0.f};

        #pragma unroll
        for (int kt = 0; kt < 4; ++kt) {
            #pragma unroll
            for (int kk = 0; kk < 2; ++kk) {
                const char* p_ = lds + cur + kt * 8192 + (wr * 32 + r16) * 128;
                const int sw = kk ? sw1 : sw0;
                f16x8 a0 = *(const f16x8*)(p_ + sw);
                f16x8 a1 = *(const f16x8*)(p_ + 2048 + sw);
                #pragma unroll
                for (int nj = 0; nj < 4; ++nj) {
                    acc[0][nj] = __builtin_amdgcn_mfma_f32_16x16x32_f16(
                        a0, bR[kt][kk][nj], acc[0][nj], 0, 0, 0);
                    acc[1][nj] = __builtin_amdgcn_mfma_f32_16x16x32_f16(
                        a1, bR[kt][kk][nj], acc[1][nj], 0, 0, 0);
                }
            }
        }

        // epilogue: per-q max over this wave's two 16-row frags (32-row group)
        float cm[4] = {-FLT_MAX, -FLT_MAX, -FLT_MAX, -FLT_MAX};
        #pragma unroll
        for (int mi = 0; mi < 2; ++mi)
            #pragma unroll
            for (int jj = 0; jj < 4; ++jj)
                #pragma unroll
                for (int nj = 0; nj < 4; ++nj)
                    cm[nj] = fmaxf(cm[nj], acc[mi][nj][jj]);
        #pragma unroll
        for (int nj = 0; nj < 4; ++nj) {
            float v = cm[nj];
            v = fmaxf(v, __shfl_xor(v, 16));
            v = fmaxf(v, __shfl_xor(v, 32));
            if (lane < 16) {
                int qn = qt * 256 + wc * 64 + nj * 16 + lane;
                __half h = __float2half(v);
                bmaxH[(size_t)qn * GSTR + mtile * 2 + wr] = *(unsigned short*)&h;
            }
        }
        if (t + 1 < nt) { VMCNT(4); BAR; }   // next tile's 4 loads done (stores newer)
    }
}

// Phase B: s1 scan + candidate collection (32-row groups, fp16 bmax) + exact
// fp32 rescore with recomputed norms; tie-break = lowest index (np.argmax).
__global__ __launch_bounds__(256) void phaseB_kernel(
    const float* __restrict__ q, const float* __restrict__ g,
    const unsigned short* __restrict__ bmaxH,
    const int* __restrict__ cat, const int* __restrict__ shp,
    int* __restrict__ out)
{
    __shared__ __align__(16) float qrow[DIM];
    __shared__ int glist[NG];
    __shared__ int ng;
    __shared__ float smax[4];
    __shared__ float rbs[4];
    __shared__ int rbi[4];

    const int qi = blockIdx.x;
    const int tid = threadIdx.x;
    const int lane = tid & 63, wid = tid >> 6;
    const __half* bm = (const __half*)(bmaxH + (size_t)qi * GSTR);
    if (tid < 64)
        *(float4*)&qrow[tid * 4] = *(const float4*)(q + (size_t)qi * DIM + tid * 4);
    if (tid == 0) ng = 0;

    float m = -FLT_MAX;
    for (int gr = tid; gr < NG; gr += 256)
        m = fmaxf(m, __half2float(bm[gr]));
    #pragma unroll
    for (int o = 32; o; o >>= 1) m = fmaxf(m, __shfl_xor(m, o));
    if (lane == 0) smax[wid] = m;
    __syncthreads();
    const float thr = fmaxf(fmaxf(smax[0], smax[1]), fmaxf(smax[2], smax[3])) - MARGIN;

    for (int gr = tid; gr < NG; gr += 256)
        if (__half2float(bm[gr]) >= thr)
            glist[atomicAdd(&ng, 1)] = gr;
    __syncthreads();

    float bs = -FLT_MAX;
    int bi = 0x7fffffff;
    const int r = tid >> 3, p = tid & 7;    // 32 rows x 8 dim-slices
    const int n = ng;
    for (int i = 0; i < n; ++i) {
        int mm = glist[i] * 32 + r;
        if (mm < M_G) {
            const float* grow = g + (size_t)mm * DIM + p * 32;
            const float* qr = qrow + p * 32;
            float s = 0.f, ssq = 0.f;
            #pragma unroll
            for (int jj = 0; jj < 8; ++jj) {
                float4 gv = *(const float4*)(grow + jj * 4);
                float4 qv = *(const float4*)(qr + jj * 4);
                s += gv.x * qv.x + gv.y * qv.y + gv.z * qv.z + gv.w * qv.w;
                ssq += gv.x * gv.x + gv.y * gv.y + gv.z * gv.z + gv.w * gv.w;
            }
            s += __shfl_xor(s, 1);  s += __shfl_xor(s, 2);  s += __shfl_xor(s, 4);
            ssq += __shfl_xor(ssq, 1); ssq += __shfl_xor(ssq, 2); ssq += __shfl_xor(ssq, 4);
            s *= 1.0f / fmaxf(sqrtf(ssq), 1e-12f);
            if (p == 0 && (s > bs || (s == bs && mm < bi))) { bs = s; bi = mm; }
        }
    }
    #pragma unroll
    for (int o = 1; o < 64; o <<= 1) {
        float os = __shfl_xor(bs, o);
        int oi = __shfl_xor(bi, o);
        if (os > bs || (os == bs && oi < bi)) { bs = os; bi = oi; }
    }
    if (lane == 0) { rbs[wid] = bs; rbi[wid] = bi; }
    __syncthreads();
    if (tid == 0) {
        #pragma unroll
        for (int ww = 1; ww < 4; ++ww)
            if (rbs[ww] > bs || (rbs[ww] == bs && rbi[ww] < bi)) { bs = rbs[ww]; bi = rbi[ww]; }
        out[qi] = cat[bi];
        out[N_Q + qi] = shp[bi];
    }
}

extern "C" void kernel_launch(void* const* d_in, const int* in_sizes, int n_in,
                              void* d_out, int out_size, void* d_ws, size_t ws_size,
                              hipStream_t stream) {
    const float* q = (const float*)d_in[0];    // [2048,256] fp32
    const float* g = (const float*)d_in[1];    // [100000,256] fp32
    const int* cat = (const int*)d_in[2];      // [100000] int32
    const int* shp = (const int*)d_in[3];      // [100000] int32
    int* out = (int*)d_out;                    // [2048 cat | 2048 shape] int32

    char* ws = (char*)d_ws;
    uint4* gp            = (uint4*)(ws + WS_GP);
    uint4* qp            = (uint4*)(ws + WS_QP);
    unsigned short* bmaxH = (unsigned short*)(ws + WS_BM);

    hipFuncSetAttribute((const void*)scoreA_kernel,
                        hipFuncAttributeMaxDynamicSharedMemorySize, 65536);

    pack_kernel<<<M_PAD / 4 + N_Q / 4, 256, 0, stream>>>(g, q, gp, qp);
    scoreA_kernel<<<256, 512, 65536, stream>>>(gp, qp, bmaxH);
    phaseB_kernel<<<N_Q, 256, 0, stream>>>(q, g, bmaxH, cat, shp, out);
}